// Round 8
// baseline (240.011 us; speedup 1.0000x reference)
//
#include <hip/hip_runtime.h>

// Problem constants
#define BB 16
#define NL 256
#define RR 24
#define LL 32
#define NN (NL*NL)        // 65536
#define BNN (BB*NN)       // 1048576
#define TT 64             // FW tile

// Output layout (float32), reference return order.
#define O_TDT 0
#define O_RT  16
#define O_TAT 32
#define O_TD  96
#define O_UNS 112
#define O_TTR 128
#define O_TT  144
#define O_ND  1048720

// Packed (dist, hops) in one f64: v = dist + hops * 2^-30.
// dists exact multiples of 2^-17; hops << 2^13; dist < 2^23 -> packing exact
// in 53-bit mantissa; f64 add distributes; f64 min = lexicographic.
// "Infinity" = qNaN pattern 0x7FF07FF07FF07FF0 (memset-able 4B pattern):
// NaN+x=NaN, IEEE fmin(NaN,x)=x, ull-atomicMin: NaN bits > any finite packed.
#define HSC 9.3132257461547852e-10   // 2^-30
#define H2  1073741824.0             // 2^30
#define HMASK 8191

// LDS: rows of 64 doubles, 16B (double2) chunks XOR-swizzled by row.
// Bank quad of a chunk = low3(physical chunk); row contributes 0 (stride 128dw).
#define RIDX(r, c2) (((r)<<6) + ((((c2) ^ ((r)&31)))<<1))
#define LDD(A, r, c2) (*(double2*)&A[RIDX((r),(c2))])
#define ELEM(A, r, c) A[RIDX((r), (c)>>1) + ((c)&1)]

// ---------------- route edges + diag zeros: one wave per (b,r) ---------------
__global__ void k_routes(const float* __restrict__ dtm, const int* __restrict__ routes,
                         unsigned long long* __restrict__ dist, float* __restrict__ acc){
    int br = blockIdx.x; int b = br / RR, r = br % RR;
    int lane = threadIdx.x;
    // diag zeros (first 64 blocks cover 16*256 entries); benign vs atomicMin
    int gid = br*64 + lane;
    if (gid < BB*NL){
        int bq = gid >> 8, n = gid & 255;
        ((double*)dist)[bq*NN + n*(NL+1)] = 0.0;
    }
    __shared__ int   s[LL];
    __shared__ float lf[LL], lr[LL], cf[LL], cr[LL];
    if (lane < LL) s[lane] = routes[(b*RR + r)*LL + lane];
    __syncthreads();
    if (lane < LL-1){
        int a0 = s[lane], a1 = s[lane+1];
        const float* dt = dtm + b*NN;
        lf[lane] = dt[a0*NL + a1] + 60.0f;   // MEAN_STOP_TIME_S
        lr[lane] = dt[a1*NL + a0] + 60.0f;
    }
    __syncthreads();
    if (lane == 0){
        float af = 0.f, ar2 = 0.f;
        cf[0] = 0.f; cr[0] = 0.f;
        for (int l = 0; l < LL-1; l++){
            af += lf[l]; ar2 += lr[l];
            cf[l+1] = af; cr[l+1] = ar2;
        }
        atomicAdd(&acc[b*16 + 1], af + ar2);  // total_route_time
    }
    __syncthreads();
    for (int p = lane; p < LL*LL; p += 64){
        int i = p >> 5, j = p & 31;
        if (j > i){
            double vf = (double)(cf[j] - cf[i]) + HSC;   // hops = 1
            double vr = (double)(cr[j] - cr[i]) + HSC;
            atomicMin(&dist[b*NN + s[i]*NL + s[j]], (unsigned long long)__double_as_longlong(vf));
            atomicMin(&dist[b*NN + s[j]*NL + s[i]], (unsigned long long)__double_as_longlong(vr));
        }
    }
}

// ---------------- one full FW round; FINAL fuses the epilogue ----------------
// dst(ti,tj) = min(D0, C0 (x) K* (x) B0) on packed f64; 512 thr, 2x4/thread.
// Column ownership {cA, cA+16} (cols 2cA,2cA+1, 2cA+32,2cA+33): uniform-row
// b-reads hit 16 chunks spanning all 8 bank quads = 2-way (free). p2 col strip
// is scalar 4-rows-per-wave (R2-proven 40K-conflict pattern).
template<bool FINAL>
__global__ __launch_bounds__(512) void k_fw(
        const double* __restrict__ src, double* __restrict__ dst, int kb,
        const float* __restrict__ demand, float* __restrict__ out,
        float* __restrict__ acc){
    int b  = blockIdx.y;
    int m  = blockIdx.x;
    int ti = m >> 2, tj = m & 3;
    int t  = threadIdx.x;
    int rp = (t >> 4) * 2;         // 2 owned rows: rp, rp+1
    int cA = t & 15, cB = cA + 16; // owned chunks
    int j0 = 2*cA, j1 = 2*cA + 32; // owned col bases
    __shared__ __align__(16) double KD[4096];   // K -> K*; later C0
    __shared__ __align__(16) double BD[4096];   // B0; later M = K* (x) B0
    const double* Kg = src + b*NN + kb*TT*(NL+1);
    const double* Bg = src + b*NN + (kb*NL + tj)*TT;
    const double* Cg = src + b*NN + (ti*NL + kb)*TT;
    const double* Dg = src + b*NN + (ti*NL + tj)*TT;

    // ---- early prefetch C0 (staging layout) and D0 (own layout) ----
    double2 c0r[4];
    #pragma unroll
    for (int u = 0; u < 4; u++){
        int fid = u*512 + t, row = fid >> 5, cc = fid & 31;
        c0r[u] = *(const double2*)(Cg + row*NL + cc*2);
    }
    double2 d0a[2], d0b[2];
    #pragma unroll
    for (int i = 0; i < 2; i++){
        d0a[i] = *(const double2*)(Dg + (rp+i)*NL + j0);
        d0b[i] = *(const double2*)(Dg + (rp+i)*NL + j1);
    }

    // ---- stage K and B0 into LDS ----
    #pragma unroll
    for (int u = 0; u < 4; u++){
        int fid = u*512 + t, row = fid >> 5, cc = fid & 31;
        LDD(KD, row, cc) = *(const double2*)(Kg + row*NL + cc*2);
        LDD(BD, row, cc) = *(const double2*)(Bg + row*NL + cc*2);
    }
    __syncthreads();

    // ---- in-LDS hierarchical closure of K (sub-tile 16, 4 sub-rounds) ----
    for (int skb = 0; skb < 4; skb++){
        int s0 = skb*16, sc2 = skb*8;
        // p1: wave 0 closes the 16x16 diag sub-tile via shfl (no barriers)
        if (t < 64){
            int i = t >> 2, jg = t & 3, rr = s0 + i, cbk = sc2 + jg*2;
            double2 m0 = LDD(KD, rr, cbk), m1 = LDD(KD, rr, cbk+1);
            double md4[4] = {m0.x, m0.y, m1.x, m1.y};
            #pragma unroll
            for (int k = 0; k < 16; k++){
                double rd[4];
                #pragma unroll
                for (int c = 0; c < 4; c++) rd[c] = __shfl(md4[c], (k<<2)|jg);
                double cd = __shfl(md4[k&3], (i<<2)|(k>>2));
                #pragma unroll
                for (int c = 0; c < 4; c++) md4[c] = fmin(md4[c], cd + rd[c]);
            }
            LDD(KD, rr, cbk)   = make_double2(md4[0], md4[1]);
            LDD(KD, rr, cbk+1) = make_double2(md4[2], md4[3]);
        }
        __syncthreads();
        // p2: t<256 vectorized row strip (16 band rows x 64 cols, 2-way reads);
        // t>=256 scalar col strip (64 rows x 16 band cols, 4 rows/wave; per-k
        // a-reads broadcast 4 rows, b-reads 1/quad). Band-square double-write
        // is a benign same-value race. Barriers in the common path.
        double rsv[4], csv[4];
        int pr = 0, pcA = 0, pcB = 0, cq = 0, ccol = 0;
        if (t < 256){
            pr = s0 + (t >> 4); pcA = t & 15; pcB = pcA + 16;
            double2 v0 = LDD(KD, pr, pcA), v1 = LDD(KD, pr, pcB);
            rsv[0]=v0.x; rsv[1]=v0.y; rsv[2]=v1.x; rsv[3]=v1.y;
            double av[16];
            #pragma unroll
            for (int c = 0; c < 8; c++){
                double2 a2 = LDD(KD, pr, sc2 + c);   // diag-closed square row
                av[2*c] = a2.x; av[2*c+1] = a2.y;
            }
            #pragma unroll
            for (int k = 0; k < 16; k++){
                double2 b0 = LDD(KD, s0+k, pcA), b1 = LDD(KD, s0+k, pcB);  // pre-strip
                rsv[0] = fmin(rsv[0], av[k] + b0.x);
                rsv[1] = fmin(rsv[1], av[k] + b0.y);
                rsv[2] = fmin(rsv[2], av[k] + b1.x);
                rsv[3] = fmin(rsv[3], av[k] + b1.y);
            }
        } else {
            int t2 = t - 256;
            cq = t2 >> 4;               // row base: rows cq, cq+16, cq+32, cq+48
            ccol = s0 + (t2 & 15);      // band col
            #pragma unroll
            for (int u = 0; u < 4; u++) csv[u] = ELEM(KD, cq + u*16, ccol);
            #pragma unroll
            for (int k = 0; k < 16; k++){
                double bk = ELEM(KD, s0+k, ccol);    // diag-closed square
                #pragma unroll
                for (int u = 0; u < 4; u++){
                    double au = ELEM(KD, cq + u*16, s0+k);   // pre-strip
                    csv[u] = fmin(csv[u], au + bk);
                }
            }
        }
        __syncthreads();   // all p2 reads done
        if (t < 256){
            LDD(KD, pr, pcA) = make_double2(rsv[0], rsv[1]);
            LDD(KD, pr, pcB) = make_double2(rsv[2], rsv[3]);
        } else {
            #pragma unroll
            for (int u = 0; u < 4; u++) ELEM(KD, cq + u*16, ccol) = csv[u];
        }
        __syncthreads();
        // p3: full 64x64, 2x4 per thread, k over the closed 16-band
        double dd[2][4];
        #pragma unroll
        for (int i = 0; i < 2; i++){
            double2 v0 = LDD(KD, rp+i, cA), v1 = LDD(KD, rp+i, cB);
            dd[i][0]=v0.x; dd[i][1]=v0.y; dd[i][2]=v1.x; dd[i][3]=v1.y;
        }
        #pragma unroll
        for (int q4 = 0; q4 < 4; q4++){
            int kr = s0 + q4*4;
            double a[2][4], bm[4][4];
            #pragma unroll
            for (int i = 0; i < 2; i++){
                double2 a0 = LDD(KD, rp+i, sc2+q4*2), a1 = LDD(KD, rp+i, sc2+q4*2+1);
                a[i][0]=a0.x; a[i][1]=a0.y; a[i][2]=a1.x; a[i][3]=a1.y;
            }
            #pragma unroll
            for (int q = 0; q < 4; q++){
                double2 b0 = LDD(KD, kr+q, cA), b1 = LDD(KD, kr+q, cB);
                bm[q][0]=b0.x; bm[q][1]=b0.y; bm[q][2]=b1.x; bm[q][3]=b1.y;
            }
            #pragma unroll
            for (int q = 0; q < 4; q++)
            #pragma unroll
            for (int i = 0; i < 2; i++)
            #pragma unroll
            for (int j = 0; j < 4; j++)
                dd[i][j] = fmin(dd[i][j], a[i][q] + bm[q][j]);
        }
        __syncthreads();   // all p3 reads done
        #pragma unroll
        for (int i = 0; i < 2; i++){
            LDD(KD, rp+i, cA) = make_double2(dd[i][0], dd[i][1]);
            LDD(KD, rp+i, cB) = make_double2(dd[i][2], dd[i][3]);
        }
        __syncthreads();
    }

    // ---- M = K* (x) B0 (K* 0-diag -> includes identity), 2x4, k-blocked ----
    double nanv = __longlong_as_double(0x7FF07FF07FF07FF0LL);
    double md[2][4];
    #pragma unroll
    for (int i = 0; i < 2; i++)
    #pragma unroll
    for (int j = 0; j < 4; j++) md[i][j] = nanv;
    #pragma unroll 4
    for (int q4 = 0; q4 < 16; q4++){
        int kr = q4*4;
        double a[2][4], bm[4][4];
        #pragma unroll
        for (int i = 0; i < 2; i++){
            double2 a0 = LDD(KD, rp+i, q4*2), a1 = LDD(KD, rp+i, q4*2+1);
            a[i][0]=a0.x; a[i][1]=a0.y; a[i][2]=a1.x; a[i][3]=a1.y;
        }
        #pragma unroll
        for (int q = 0; q < 4; q++){
            double2 b0 = LDD(BD, kr+q, cA), b1 = LDD(BD, kr+q, cB);
            bm[q][0]=b0.x; bm[q][1]=b0.y; bm[q][2]=b1.x; bm[q][3]=b1.y;
        }
        #pragma unroll
        for (int q = 0; q < 4; q++)
        #pragma unroll
        for (int i = 0; i < 2; i++)
        #pragma unroll
        for (int j = 0; j < 4; j++)
            md[i][j] = fmin(md[i][j], a[i][q] + bm[q][j]);
    }
    __syncthreads();   // all K*/B0 reads done
    // write M over B0; write prefetched C0 over K*
    #pragma unroll
    for (int i = 0; i < 2; i++){
        LDD(BD, rp+i, cA) = make_double2(md[i][0], md[i][1]);
        LDD(BD, rp+i, cB) = make_double2(md[i][2], md[i][3]);
    }
    #pragma unroll
    for (int u = 0; u < 4; u++){
        int fid = u*512 + t, row = fid >> 5, cc = fid & 31;
        LDD(KD, row, cc) = c0r[u];
    }
    __syncthreads();

    // ---- dst = min(D0, C0 (x) M), 2x4, k-blocked ----
    double dd[2][4];
    #pragma unroll
    for (int i = 0; i < 2; i++){
        dd[i][0]=d0a[i].x; dd[i][1]=d0a[i].y; dd[i][2]=d0b[i].x; dd[i][3]=d0b[i].y;
    }
    #pragma unroll 4
    for (int q4 = 0; q4 < 16; q4++){
        int kr = q4*4;
        double a[2][4], bm[4][4];
        #pragma unroll
        for (int i = 0; i < 2; i++){
            double2 a0 = LDD(KD, rp+i, q4*2), a1 = LDD(KD, rp+i, q4*2+1);
            a[i][0]=a0.x; a[i][1]=a0.y; a[i][2]=a1.x; a[i][3]=a1.y;
        }
        #pragma unroll
        for (int q = 0; q < 4; q++){
            double2 b0 = LDD(BD, kr+q, cA), b1 = LDD(BD, kr+q, cB);
            bm[q][0]=b0.x; bm[q][1]=b0.y; bm[q][2]=b1.x; bm[q][3]=b1.y;
        }
        #pragma unroll
        for (int q = 0; q < 4; q++)
        #pragma unroll
        for (int i = 0; i < 2; i++)
        #pragma unroll
        for (int j = 0; j < 4; j++)
            dd[i][j] = fmin(dd[i][j], a[i][q] + bm[q][j]);
    }

    if (!FINAL){
        double* Od = dst + b*NN + (ti*NL + tj)*TT;
        #pragma unroll
        for (int i = 0; i < 2; i++){
            *(double2*)(Od + (rp+i)*NL + j0) = make_double2(dd[i][0], dd[i][1]);
            *(double2*)(Od + (rp+i)*NL + j1) = make_double2(dd[i][2], dd[i][3]);
        }
        return;
    }

    // ---- fused epilogue (FINAL): no dist write; stats straight from regs ----
    float s9[9];
    #pragma unroll
    for (int q = 0; q < 9; q++) s9[q] = 0.f;
    #pragma unroll
    for (int i = 0; i < 2; i++){
        const float* dmg = demand + b*NN + (ti*TT + rp + i)*NL + tj*TT;
        float* ttg = out + O_TT + b*NN + (ti*TT + rp + i)*NL + tj*TT;
        float2 m0 = *(const float2*)(dmg + j0);
        float2 m1 = *(const float2*)(dmg + j1);
        float dmv[4] = {m0.x, m0.y, m1.x, m1.y};
        float tts[4];
        #pragma unroll
        for (int e = 0; e < 4; e++){
            double v = dd[i][e];
            bool np = !(v < 1e37);
            double vv = np ? 0.0 : v;
            int h = (int)(((long long)(vv * H2)) & (long long)HMASK);
            float d = (float)vv;
            float dm = dmv[e];
            float pl = np ? 0.f : (float)(h + 1);
            float tr = (pl == 0.f) ? 0.f : pl - 2.f;
            float tt = np ? 0.f : d + tr*300.f;   // AVG_TRANSFER_WAIT_TIME_S
            tts[e] = tt;
            s9[0] += dm*tt;
            s9[1] += dm*tr;
            s9[2] += np ? dm : 0.f;
            s9[3] += dm;
            s9[4] += (np && dm > 0.f) ? 1.f : 0.f;
            s9[5] += (tr == 0.f) ? dm : 0.f;
            s9[6] += (tr == 1.f) ? dm : 0.f;
            s9[7] += (tr == 2.f) ? dm : 0.f;
            s9[8] += (tr > 2.f) ? dm : 0.f;
        }
        *(float2*)(ttg + j0) = make_float2(tts[0], tts[1]);
        *(float2*)(ttg + j1) = make_float2(tts[2], tts[3]);
    }
    #define RED(x) { x += __shfl_down(x,32); x += __shfl_down(x,16); x += __shfl_down(x,8); \
                     x += __shfl_down(x,4);  x += __shfl_down(x,2);  x += __shfl_down(x,1); }
    #pragma unroll
    for (int q = 0; q < 9; q++) RED(s9[q])
    __syncthreads();   // done with KD reads; reuse as reduction scratch
    float* red = (float*)KD;
    int w = t >> 6, lane = t & 63;
    if (lane == 0){
        #pragma unroll
        for (int q = 0; q < 9; q++) red[w*9 + q] = s9[q];
    }
    __syncthreads();
    if (t < 9){
        float v = 0.f;
        #pragma unroll
        for (int ww = 0; ww < 8; ww++) v += red[ww*9 + t];
        // acc slots: 0 tdt, 1 rt, 2 ttrans, 3 uns, 4 tdem, 5 ndis, 6 b0, 7 b1, 8 b2, 9 bun
        int slot = (t == 0) ? 0 : t + 1;
        atomicAdd(&acc[b*16 + slot], v);
    }
    __syncthreads();
    __shared__ int isLast;
    if (t == 0){
        unsigned prev = atomicAdd((unsigned int*)(acc + 255), 1u);
        isLast = (prev == 255u) ? 1 : 0;   // 256 blocks
    }
    __syncthreads();
    if (isLast && t < BB){
        int bb = t;
        float a[10];
        #pragma unroll
        for (int s = 0; s < 10; s++) a[s] = atomicAdd(&acc[bb*16 + s], 0.f);  // coherent read
        out[O_TDT + bb] = a[0];
        out[O_RT  + bb] = a[1];
        out[O_TAT + 4*bb + 0] = a[6];
        out[O_TAT + 4*bb + 1] = a[7];
        out[O_TAT + 4*bb + 2] = a[8];
        out[O_TAT + 4*bb + 3] = a[9] + a[3];
        out[O_TD  + bb] = a[4];
        out[O_UNS + bb] = a[3];
        out[O_TTR + bb] = a[2];
        out[O_ND  + bb] = a[5];
    }
}

extern "C" void kernel_launch(void* const* d_in, const int* in_sizes, int n_in,
                              void* d_out, int out_size, void* d_ws, size_t ws_size,
                              hipStream_t stream){
    (void)in_sizes; (void)n_in; (void)out_size; (void)ws_size;
    const float* dtm    = (const float*)d_in[0];
    const float* demand = (const float*)d_in[1];
    const int*   routes = (const int*)d_in[2];
    float* out = (float*)d_out;
    double* distA = (double*)d_ws;          // buf0 packed (dist,hops)
    double* distB = distA + BNN;            // buf1 packed
    float*  acc   = (float*)(distB + BNN);  // 256 floats (incl. counter at [255])

    // dist = qNaN pattern ("infinity" for this algebra), acc = 0
    hipMemsetD32Async((hipDeviceptr_t)distA, 0x7FF07FF0u, (size_t)BNN*2, stream);
    hipMemsetAsync(acc, 0, 256*sizeof(float), stream);
    k_routes<<<BB*RR, 64, 0, stream>>>(dtm, routes, (unsigned long long*)distA, acc);
    // 4 rounds, double-buffered; final round fuses the epilogue (no dist write)
    k_fw<false><<<dim3(16,BB), 512, 0, stream>>>(distA, distB, 0, nullptr, nullptr, nullptr);
    k_fw<false><<<dim3(16,BB), 512, 0, stream>>>(distB, distA, 1, nullptr, nullptr, nullptr);
    k_fw<false><<<dim3(16,BB), 512, 0, stream>>>(distA, distB, 2, nullptr, nullptr, nullptr);
    k_fw<true> <<<dim3(16,BB), 512, 0, stream>>>(distB, nullptr, 3, demand, out, acc);
}